// Round 2
// baseline (442.587 us; speedup 1.0000x reference)
//
#include <hip/hip_runtime.h>
#include <stdint.h>

#define B_ 2
#define T_ 2048
#define C_ 2048
#define NH 16
#define NG 4
#define HS 128

typedef unsigned short u16;
typedef __bf16 bf16_t;
typedef bf16_t bf16x8 __attribute__((ext_vector_type(8)));
typedef float f32x4 __attribute__((ext_vector_type(4)));

__device__ __forceinline__ u16 f2bf(float f) {
    union { float f; uint32_t u; } v; v.f = f;
    uint32_t r = (v.u + 0x7fffu + ((v.u >> 16) & 1u)) >> 16;
    return (u16)r;
}
__device__ __forceinline__ float bf2f(u16 h) {
    union { uint32_t u; float f; } v; v.u = ((uint32_t)h) << 16;
    return v.f;
}

// ---------------- elementwise fp32 -> bf16 ----------------
__global__ void k_f32_to_bf16(const float* __restrict__ in, u16* __restrict__ out, int n4) {
    int i = blockIdx.x * blockDim.x + threadIdx.x;
    if (i < n4) {
        float4 f = ((const float4*)in)[i];
        ushort4 o;
        o.x = f2bf(f.x); o.y = f2bf(f.y); o.z = f2bf(f.z); o.w = f2bf(f.w);
        ((ushort4*)out)[i] = o;
    }
}

// ---------------- transpose + convert: Wt[n][k] = bf16(W[k][n]) ----------------
__global__ void k_transpose_bf16(const float* __restrict__ W, u16* __restrict__ Wt, int K, int N) {
    __shared__ float tile[32][33];
    int n0 = blockIdx.x * 32, k0 = blockIdx.y * 32;
    int tx = threadIdx.x & 31, ty = threadIdx.x >> 5; // ty in [0,8)
#pragma unroll
    for (int i = 0; i < 4; i++) {
        int r = ty + i * 8;
        tile[r][tx] = W[(size_t)(k0 + r) * N + (n0 + tx)];
    }
    __syncthreads();
#pragma unroll
    for (int i = 0; i < 4; i++) {
        int r = ty + i * 8;
        Wt[(size_t)(n0 + r) * K + (k0 + tx)] = f2bf(tile[tx][r]);
    }
}

// ---------------- GEMM: C[M][N] = A[M][K] * Bt[N][K]^T, bf16 in, fp32 acc ----------------
// m97 structure: 128x128 tile, BK=32, 256 threads, global_load_lds width 16.
template <typename OutT>
__global__ __launch_bounds__(256) void k_gemm_bt(const u16* __restrict__ A,
                                                 const u16* __restrict__ Bt,
                                                 OutT* __restrict__ C,
                                                 int M, int N, int K) {
    __shared__ __align__(16) u16 As[128 * 32];
    __shared__ __align__(16) u16 Bs[128 * 32];
    const int tid = threadIdx.x;
    const int wave = tid >> 6, lane = tid & 63;
    const int quad = lane >> 4, l16 = lane & 15;
    const int wr = wave >> 1, wc = wave & 1;
    const int m0 = blockIdx.y * 128, n0 = blockIdx.x * 128;

    f32x4 acc[4][4] = {};

    for (int k0 = 0; k0 < K; k0 += 32) {
        __syncthreads();
#pragma unroll
        for (int i = 0; i < 2; i++) {
            int c = tid + i * 256;            // 16B chunk id in [0,512)
            int row = c >> 2, seg = c & 3;    // tile row, k-quarter (32 u16 = 4 chunks/row)
            const u16* ga = A + (size_t)(m0 + row) * K + k0 + seg * 8;
            const u16* gb = Bt + (size_t)(n0 + row) * K + k0 + seg * 8;
            __builtin_amdgcn_global_load_lds((const __attribute__((address_space(1))) void*)ga,
                                             (__attribute__((address_space(3))) void*)&As[c * 8],
                                             16, 0, 0);
            __builtin_amdgcn_global_load_lds((const __attribute__((address_space(1))) void*)gb,
                                             (__attribute__((address_space(3))) void*)&Bs[c * 8],
                                             16, 0, 0);
        }
        __syncthreads();
        bf16x8 a[4], b[4];
#pragma unroll
        for (int mi = 0; mi < 4; mi++)
            a[mi] = *(const bf16x8*)&As[(wr * 64 + mi * 16 + l16) * 32 + quad * 8];
#pragma unroll
        for (int ni = 0; ni < 4; ni++)
            b[ni] = *(const bf16x8*)&Bs[(wc * 64 + ni * 16 + l16) * 32 + quad * 8];
#pragma unroll
        for (int mi = 0; mi < 4; mi++)
#pragma unroll
            for (int ni = 0; ni < 4; ni++)
                acc[mi][ni] = __builtin_amdgcn_mfma_f32_16x16x32_bf16(a[mi], b[ni], acc[mi][ni], 0, 0, 0);
    }
    // epilogue: C/D layout col=lane&15, row=quad*4+reg
#pragma unroll
    for (int mi = 0; mi < 4; mi++)
#pragma unroll
        for (int ni = 0; ni < 4; ni++)
#pragma unroll
            for (int r = 0; r < 4; r++) {
                int row = m0 + wr * 64 + mi * 16 + quad * 4 + r;
                int col = n0 + wc * 64 + ni * 16 + l16;
                float v = acc[mi][ni][r];
                if constexpr (sizeof(OutT) == 2)
                    C[(size_t)row * N + col] = (OutT)f2bf(v);
                else
                    C[(size_t)row * N + col] = v;
            }
}

// ---------------- RoPE + pack q/k/v ----------------
// qkv: [b*T + t][3072], per group g: [q0,q1,q2,q3,k,v] x 128
// qa: [b][h][t][128], ka: [b][g][t][128], vt: [b][g][d][T] (transposed)
__global__ void k_rope_pack(const u16* __restrict__ qkv, const float* __restrict__ cosb,
                            const float* __restrict__ sinb, u16* __restrict__ qa,
                            u16* __restrict__ ka, u16* __restrict__ vt) {
    int idx = blockIdx.x * blockDim.x + threadIdx.x; // B*T*NG*64 = 2^20
    int d = idx & 63;
    int g = (idx >> 6) & 3;
    int t = (idx >> 8) & 2047;
    int b = idx >> 19;
    float c = cosb[t * 64 + d], s = sinb[t * 64 + d];
    size_t rowb = ((size_t)(b * T_ + t)) * 3072 + g * 768;
#pragma unroll
    for (int p = 0; p < 4; p++) {
        float x1 = bf2f(qkv[rowb + p * 128 + d]);
        float x2 = bf2f(qkv[rowb + p * 128 + d + 64]);
        int h = g * 4 + p;
        size_t q0 = (((size_t)(b * NH + h)) * T_ + t) * 128;
        qa[q0 + d] = f2bf(x1 * c - x2 * s);
        qa[q0 + d + 64] = f2bf(x1 * s + x2 * c);
    }
    {
        float x1 = bf2f(qkv[rowb + 4 * 128 + d]);
        float x2 = bf2f(qkv[rowb + 4 * 128 + d + 64]);
        size_t k0 = (((size_t)(b * NG + g)) * T_ + t) * 128;
        ka[k0 + d] = f2bf(x1 * c - x2 * s);
        ka[k0 + d + 64] = f2bf(x1 * s + x2 * c);
    }
    {
        u16 v1 = qkv[rowb + 5 * 128 + d];
        u16 v2 = qkv[rowb + 5 * 128 + d + 64];
        size_t vb = ((size_t)(b * NG + g)) * 128;
        vt[(vb + d) * T_ + t] = v1;
        vt[(vb + d + 64) * T_ + t] = v2;
    }
}

// ---------------- flash attention (non-causal), 64 q-rows/block, 64-key tiles ----------------
__global__ __launch_bounds__(256) void k_attn(const u16* __restrict__ qa,
                                              const u16* __restrict__ ka,
                                              const u16* __restrict__ vt,
                                              u16* __restrict__ ya) {
    __shared__ __align__(16) u16 Ks[64 * 136];   // [key][d], pad 8
    __shared__ __align__(16) u16 Vs[128 * 72];   // [d][key], pad 8
    __shared__ __align__(16) u16 Ps[4 * 16 * 72]; // per-wave P tile [q][key], pad 8
    const int tid = threadIdx.x;
    const int wave = tid >> 6, lane = tid & 63;
    const int quad = lane >> 4, l16 = lane & 15;
    const int qt = blockIdx.x, h = blockIdx.y, b = blockIdx.z;
    const int g = h >> 2;
    const float scale = 0.08838834764831845f;

    // Q fragments register-resident: A-layout m=l16, k=ks*32+quad*8
    bf16x8 qf[4];
    {
        const u16* qrow = qa + (((size_t)(b * NH + h)) * T_ + qt * 64 + wave * 16 + l16) * 128;
#pragma unroll
        for (int ks = 0; ks < 4; ks++)
            qf[ks] = *(const bf16x8*)(qrow + ks * 32 + quad * 8);
    }
    const u16* kbase = ka + ((size_t)(b * NG + g)) * T_ * 128;
    const u16* vbase = vt + ((size_t)(b * NG + g)) * 128 * T_;

    f32x4 yacc[8] = {};
    float mrow[4], lrow[4];
#pragma unroll
    for (int r = 0; r < 4; r++) { mrow[r] = -1e30f; lrow[r] = 0.f; }
    u16* Pw = &Ps[wave * 16 * 72];

    for (int kt = 0; kt < T_ / 64; kt++) {
        __syncthreads();
        // stage K tile: 64 keys x 128 d  (16 chunks of 16B per row)
#pragma unroll
        for (int i = 0; i < 4; i++) {
            int c = tid + i * 256;            // chunk id in [0,1024)
            int row = c >> 4, seg = c & 15;   // row in [0,64), seg in [0,16)
            *(uint4*)&Ks[row * 136 + seg * 8] =
                *(const uint4*)(kbase + (size_t)(kt * 64 + row) * 128 + seg * 8);
        }
        // stage V^T tile: 128 d-rows x 64 keys (8 chunks of 16B per row)
#pragma unroll
        for (int i = 0; i < 4; i++) {
            int c = tid + i * 256;
            int row = c >> 3, seg = c & 7;    // row in [0,128), seg in [0,8)
            *(uint4*)&Vs[row * 72 + seg * 8] =
                *(const uint4*)(vbase + (size_t)row * T_ + kt * 64 + seg * 8);
        }
        __syncthreads();
        // S = Q K^T : rows=q(16), cols=keys(64)
        f32x4 sacc[4] = {};
#pragma unroll
        for (int ks = 0; ks < 4; ks++) {
#pragma unroll
            for (int ni = 0; ni < 4; ni++) {
                bf16x8 kf = *(const bf16x8*)&Ks[(ni * 16 + l16) * 136 + ks * 32 + quad * 8];
                sacc[ni] = __builtin_amdgcn_mfma_f32_16x16x32_bf16(qf[ks], kf, sacc[ni], 0, 0, 0);
            }
        }
        // online softmax, state in registers (rows quad*4+r owned by this lane group)
        float sv[4][4];
#pragma unroll
        for (int ni = 0; ni < 4; ni++)
#pragma unroll
            for (int r = 0; r < 4; r++) sv[ni][r] = sacc[ni][r] * scale;
#pragma unroll
        for (int r = 0; r < 4; r++) {
            float mx = fmaxf(fmaxf(sv[0][r], sv[1][r]), fmaxf(sv[2][r], sv[3][r]));
            mx = fmaxf(mx, __shfl_xor(mx, 1));
            mx = fmaxf(mx, __shfl_xor(mx, 2));
            mx = fmaxf(mx, __shfl_xor(mx, 4));
            mx = fmaxf(mx, __shfl_xor(mx, 8));
            float mnew = fmaxf(mrow[r], mx);
            float alpha = __expf(mrow[r] - mnew);
            mrow[r] = mnew;
            float rs = 0.f;
#pragma unroll
            for (int ni = 0; ni < 4; ni++) {
                float pv = __expf(sv[ni][r] - mnew);
                rs += pv;
                Pw[(quad * 4 + r) * 72 + ni * 16 + l16] = f2bf(pv);
            }
            rs += __shfl_xor(rs, 1);
            rs += __shfl_xor(rs, 2);
            rs += __shfl_xor(rs, 4);
            rs += __shfl_xor(rs, 8);
            lrow[r] = lrow[r] * alpha + rs;
#pragma unroll
            for (int ni = 0; ni < 8; ni++) yacc[ni][r] *= alpha;
        }
        __syncthreads();
        // yacc += P * V : A=Pw[16][64], B-operand from Vs (B[k=key][n=d] = Vs[d][key])
#pragma unroll
        for (int ks = 0; ks < 2; ks++) {
            bf16x8 pf = *(const bf16x8*)&Pw[l16 * 72 + ks * 32 + quad * 8];
#pragma unroll
            for (int ni = 0; ni < 8; ni++) {
                bf16x8 vf = *(const bf16x8*)&Vs[(ni * 16 + l16) * 72 + ks * 32 + quad * 8];
                yacc[ni] = __builtin_amdgcn_mfma_f32_16x16x32_bf16(pf, vf, yacc[ni], 0, 0, 0);
            }
        }
    }
    // epilogue: divide by l, store ya[b][t][h*128+d]
#pragma unroll
    for (int r = 0; r < 4; r++) {
        float inv = 1.f / lrow[r];
        size_t row = (size_t)(b * T_ + qt * 64 + wave * 16 + quad * 4 + r);
#pragma unroll
        for (int ni = 0; ni < 8; ni++)
            ya[row * C_ + h * 128 + ni * 16 + l16] = f2bf(yacc[ni][r] * inv);
    }
}

extern "C" void kernel_launch(void* const* d_in, const int* in_sizes, int n_in,
                              void* d_out, int out_size, void* d_ws, size_t ws_size,
                              hipStream_t stream) {
    (void)in_sizes; (void)n_in; (void)out_size; (void)ws_size;
    const float* x = (const float*)d_in[0];
    const float* cosb = (const float*)d_in[1];
    const float* sinb = (const float*)d_in[2];
    const float* w_attn = (const float*)d_in[3];
    const float* w_proj = (const float*)d_in[4];
    float* out = (float*)d_out;

    char* ws = (char*)d_ws;
    size_t off = 0;
    auto alloc = [&](size_t bytes) -> char* {
        char* p = ws + off;
        off += (bytes + 255) & ~(size_t)255;
        return p;
    };
    u16* xb  = (u16*)alloc((size_t)4096 * 2048 * 2);   // bf16 x  (reused as ya later)
    u16* wat = (u16*)alloc((size_t)3072 * 2048 * 2);   // w_attn^T bf16
    u16* wpt = (u16*)alloc((size_t)2048 * 2048 * 2);   // w_proj^T bf16
    u16* qkv = (u16*)alloc((size_t)4096 * 3072 * 2);   // qkv bf16
    u16* qa  = (u16*)alloc((size_t)B_ * NH * T_ * HS * 2);
    u16* ka  = (u16*)alloc((size_t)B_ * NG * T_ * HS * 2);
    u16* vt  = (u16*)alloc((size_t)B_ * NG * T_ * HS * 2);
    u16* ya  = xb; // xb dead after gemm1

    k_f32_to_bf16<<<dim3(8192), dim3(256), 0, stream>>>(x, xb, 4096 * 2048 / 4);
    k_transpose_bf16<<<dim3(96, 64), dim3(256), 0, stream>>>(w_attn, wat, 2048, 3072);
    k_transpose_bf16<<<dim3(64, 64), dim3(256), 0, stream>>>(w_proj, wpt, 2048, 2048);
    k_gemm_bt<u16><<<dim3(24, 32), dim3(256), 0, stream>>>(xb, wat, qkv, 4096, 3072, 2048);
    k_rope_pack<<<dim3(4096), dim3(256), 0, stream>>>(qkv, cosb, sinb, qa, ka, vt);
    k_attn<<<dim3(32, 16, 2), dim3(256), 0, stream>>>(qa, ka, vt, ya);
    k_gemm_bt<float><<<dim3(16, 32), dim3(256), 0, stream>>>(ya, wpt, out, 4096, 2048, 2048);
}

// Round 3
// 367.901 us; speedup vs baseline: 1.2030x; 1.2030x over previous
//
#include <hip/hip_runtime.h>
#include <stdint.h>

#define B_ 2
#define T_ 2048
#define C_ 2048
#define NH 16
#define NG 4
#define HS 128

typedef unsigned short u16;
typedef __bf16 bf16_t;
typedef bf16_t bf16x8 __attribute__((ext_vector_type(8)));
typedef float f32x4 __attribute__((ext_vector_type(4)));

__device__ __forceinline__ u16 f2bf(float f) {
    union { float f; uint32_t u; } v; v.f = f;
    uint32_t r = (v.u + 0x7fffu + ((v.u >> 16) & 1u)) >> 16;
    return (u16)r;
}
__device__ __forceinline__ float bf2f(u16 h) {
    union { uint32_t u; float f; } v; v.u = ((uint32_t)h) << 16;
    return v.f;
}

// ---------------- elementwise fp32 -> bf16 ----------------
__global__ void k_f32_to_bf16(const float* __restrict__ in, u16* __restrict__ out, int n4) {
    int i = blockIdx.x * blockDim.x + threadIdx.x;
    if (i < n4) {
        float4 f = ((const float4*)in)[i];
        ushort4 o;
        o.x = f2bf(f.x); o.y = f2bf(f.y); o.z = f2bf(f.z); o.w = f2bf(f.w);
        ((ushort4*)out)[i] = o;
    }
}

// ---------------- transpose + convert: Wt[n][k] = bf16(W[k][n]) ----------------
__global__ void k_transpose_bf16(const float* __restrict__ W, u16* __restrict__ Wt, int K, int N) {
    __shared__ float tile[32][33];
    int n0 = blockIdx.x * 32, k0 = blockIdx.y * 32;
    int tx = threadIdx.x & 31, ty = threadIdx.x >> 5; // ty in [0,8)
#pragma unroll
    for (int i = 0; i < 4; i++) {
        int r = ty + i * 8;
        tile[r][tx] = W[(size_t)(k0 + r) * N + (n0 + tx)];
    }
    __syncthreads();
#pragma unroll
    for (int i = 0; i < 4; i++) {
        int r = ty + i * 8;
        Wt[(size_t)(n0 + r) * K + (k0 + tx)] = f2bf(tile[tx][r]);
    }
}

// ---------------- GEMM: C[M][N] = A[M][K] * Bt[N][K]^T, bf16 in, fp32 acc ----------------
template <typename OutT>
__global__ __launch_bounds__(256) void k_gemm_bt(const u16* __restrict__ A,
                                                 const u16* __restrict__ Bt,
                                                 OutT* __restrict__ C,
                                                 int M, int N, int K) {
    __shared__ __align__(16) u16 As[128 * 32];
    __shared__ __align__(16) u16 Bs[128 * 32];
    const int tid = threadIdx.x;
    const int wave = tid >> 6, lane = tid & 63;
    const int quad = lane >> 4, l16 = lane & 15;
    const int wr = wave >> 1, wc = wave & 1;
    const int m0 = blockIdx.y * 128, n0 = blockIdx.x * 128;

    f32x4 acc[4][4] = {};

    for (int k0 = 0; k0 < K; k0 += 32) {
        __syncthreads();
#pragma unroll
        for (int i = 0; i < 2; i++) {
            int c = tid + i * 256;
            int row = c >> 2, seg = c & 3;
            const u16* ga = A + (size_t)(m0 + row) * K + k0 + seg * 8;
            const u16* gb = Bt + (size_t)(n0 + row) * K + k0 + seg * 8;
            __builtin_amdgcn_global_load_lds((const __attribute__((address_space(1))) void*)ga,
                                             (__attribute__((address_space(3))) void*)&As[c * 8],
                                             16, 0, 0);
            __builtin_amdgcn_global_load_lds((const __attribute__((address_space(1))) void*)gb,
                                             (__attribute__((address_space(3))) void*)&Bs[c * 8],
                                             16, 0, 0);
        }
        __syncthreads();
        bf16x8 a[4], b[4];
#pragma unroll
        for (int mi = 0; mi < 4; mi++)
            a[mi] = *(const bf16x8*)&As[(wr * 64 + mi * 16 + l16) * 32 + quad * 8];
#pragma unroll
        for (int ni = 0; ni < 4; ni++)
            b[ni] = *(const bf16x8*)&Bs[(wc * 64 + ni * 16 + l16) * 32 + quad * 8];
#pragma unroll
        for (int mi = 0; mi < 4; mi++)
#pragma unroll
            for (int ni = 0; ni < 4; ni++)
                acc[mi][ni] = __builtin_amdgcn_mfma_f32_16x16x32_bf16(a[mi], b[ni], acc[mi][ni], 0, 0, 0);
    }
#pragma unroll
    for (int mi = 0; mi < 4; mi++)
#pragma unroll
        for (int ni = 0; ni < 4; ni++)
#pragma unroll
            for (int r = 0; r < 4; r++) {
                int row = m0 + wr * 64 + mi * 16 + quad * 4 + r;
                int col = n0 + wc * 64 + ni * 16 + l16;
                float v = acc[mi][ni][r];
                if constexpr (sizeof(OutT) == 2)
                    C[(size_t)row * N + col] = (OutT)f2bf(v);
                else
                    C[(size_t)row * N + col] = v;
            }
}

// ---------------- RoPE + pack q/k/v ----------------
// qa: [b][h][t][128] (q pre-scaled by softmax_scale*log2e), ka: [b][g][t][128], vt: [b][g][d][T]
__global__ void k_rope_pack(const u16* __restrict__ qkv, const float* __restrict__ cosb,
                            const float* __restrict__ sinb, u16* __restrict__ qa,
                            u16* __restrict__ ka, u16* __restrict__ vt) {
    const float QS = 0.08838834764831845f * 1.44269504088896341f; // scale * log2(e)
    int idx = blockIdx.x * blockDim.x + threadIdx.x;
    int d = idx & 63;
    int g = (idx >> 6) & 3;
    int t = (idx >> 8) & 2047;
    int b = idx >> 19;
    float c = cosb[t * 64 + d], s = sinb[t * 64 + d];
    size_t rowb = ((size_t)(b * T_ + t)) * 3072 + g * 768;
#pragma unroll
    for (int p = 0; p < 4; p++) {
        float x1 = bf2f(qkv[rowb + p * 128 + d]);
        float x2 = bf2f(qkv[rowb + p * 128 + d + 64]);
        int h = g * 4 + p;
        size_t q0 = (((size_t)(b * NH + h)) * T_ + t) * 128;
        qa[q0 + d] = f2bf((x1 * c - x2 * s) * QS);
        qa[q0 + d + 64] = f2bf((x1 * s + x2 * c) * QS);
    }
    {
        float x1 = bf2f(qkv[rowb + 4 * 128 + d]);
        float x2 = bf2f(qkv[rowb + 4 * 128 + d + 64]);
        size_t k0 = (((size_t)(b * NG + g)) * T_ + t) * 128;
        ka[k0 + d] = f2bf(x1 * c - x2 * s);
        ka[k0 + d + 64] = f2bf(x1 * s + x2 * c);
    }
    {
        u16 v1 = qkv[rowb + 5 * 128 + d];
        u16 v2 = qkv[rowb + 5 * 128 + d + 64];
        size_t vb = ((size_t)(b * NG + g)) * 128;
        vt[(vb + d) * T_ + t] = v1;
        vt[(vb + d + 64) * T_ + t] = v2;
    }
}

// ---------------- flash attention, S^T formulation ----------------
// Per block: 128 q rows of one head; 4 waves x 32 q. K-tile = 64 keys.
// S^T = K*Q^T so softmax state is per-lane (q = lane&15); V is staged with
// tau-permuted key columns so S^T's C-layout registers ARE the PV B-fragment.
__global__ __launch_bounds__(256, 2) void k_attn(const u16* __restrict__ qa,
                                                 const u16* __restrict__ ka,
                                                 const u16* __restrict__ vt,
                                                 u16* __restrict__ ya) {
    __shared__ __align__(16) u16 smem[16384]; // 32 KB: Ks[0..8191] | Vs[8192..16383]
    u16* Ks = smem;
    u16* Vs = smem + 8192;
    const int tid = threadIdx.x;
    const int wave = tid >> 6, lane = tid & 63;
    const int quad = lane >> 4, l16 = lane & 15;
    const int qt = blockIdx.x, h = blockIdx.y, b = blockIdx.z;
    const int g = h >> 2;

    // Q as B-operand fragments: n=l16 (q), k=d=ks*32+quad*8+j
    bf16x8 qf[2][4];
    {
        const u16* qbase = qa + (((size_t)(b * NH + h)) * T_ + qt * 128 + wave * 32 + l16) * 128;
#pragma unroll
        for (int t16 = 0; t16 < 2; t16++)
#pragma unroll
            for (int ks = 0; ks < 4; ks++)
                qf[t16][ks] = *(const bf16x8*)(qbase + t16 * 16 * 128 + ks * 32 + quad * 8);
    }
    const u16* kbase = ka + ((size_t)(b * NG + g)) * T_ * 128;
    const u16* vbase = vt + ((size_t)(b * NG + g)) * 128 * T_;

    f32x4 yacc[2][8] = {};
    float mrow[2] = {-3e38f, -3e38f}, lrow[2] = {0.f, 0.f};

    for (int kt = 0; kt < T_ / 64; kt++) {
        __syncthreads();
        // K stage: rows=keys(64) x 128 d, 16B chunks, XOR swizzle (seg ^ row&15)
#pragma unroll
        for (int i = 0; i < 4; i++) {
            int c = tid + i * 256;
            int row = c >> 4, seg = c & 15;
            uint4 dv = *(const uint4*)(kbase + (size_t)(kt * 64 + row) * 128 + seg * 8);
            *(uint4*)&Ks[row * 128 + (seg ^ (row & 15)) * 8] = dv;
        }
        // V stage: rows=d(128) x 64 key-cols, tau-permuted: col 32ks2+8q+j holds
        // key 32ks2+16(j>>2)+4q+(j&3). 16B global load = keys m*8..m*8+7 splits
        // into two 8B halves at chunks segA, segA+1, intra-chunk offset 4a u16.
#pragma unroll
        for (int i = 0; i < 4; i++) {
            int p = tid + i * 256;
            int d = p >> 3, m = p & 7;
            uint4 dv = *(const uint4*)(vbase + (size_t)d * T_ + kt * 64 + m * 8);
            int segA = (m >> 2) * 4 + (m & 1) * 2;
            int a4 = ((m >> 1) & 1) * 4;
            *(uint2*)&Vs[d * 64 + (segA ^ (d & 7)) * 8 + a4] = make_uint2(dv.x, dv.y);
            *(uint2*)&Vs[d * 64 + ((segA + 1) ^ (d & 7)) * 8 + a4] = make_uint2(dv.z, dv.w);
        }
        __syncthreads();

        // S^T = K*Q^T : C rows = key slots, cols = q
        f32x4 sacc[2][4] = {};
#pragma unroll
        for (int ks = 0; ks < 4; ks++) {
#pragma unroll
            for (int ni = 0; ni < 4; ni++) {
                bf16x8 kf = *(const bf16x8*)&Ks[(ni * 16 + l16) * 128 + ((ks * 4 + quad) ^ l16) * 8];
                sacc[0][ni] = __builtin_amdgcn_mfma_f32_16x16x32_bf16(kf, qf[0][ks], sacc[0][ni], 0, 0, 0);
                sacc[1][ni] = __builtin_amdgcn_mfma_f32_16x16x32_bf16(kf, qf[1][ks], sacc[1][ni], 0, 0, 0);
            }
        }

        // online softmax (base-2; scale*log2e folded into Q)
        uint32_t pk[2][4][2];
#pragma unroll
        for (int t16 = 0; t16 < 2; t16++) {
            float mx = sacc[t16][0][0];
#pragma unroll
            for (int ni = 0; ni < 4; ni++)
#pragma unroll
                for (int r = 0; r < 4; r++) mx = fmaxf(mx, sacc[t16][ni][r]);
            mx = fmaxf(mx, __shfl_xor(mx, 16));
            mx = fmaxf(mx, __shfl_xor(mx, 32));
            float mnew = fmaxf(mrow[t16], mx);
            float alpha = exp2f(mrow[t16] - mnew);
            mrow[t16] = mnew;
            float rs = 0.f;
#pragma unroll
            for (int ni = 0; ni < 4; ni++) {
                float p0 = exp2f(sacc[t16][ni][0] - mnew);
                float p1 = exp2f(sacc[t16][ni][1] - mnew);
                float p2 = exp2f(sacc[t16][ni][2] - mnew);
                float p3 = exp2f(sacc[t16][ni][3] - mnew);
                rs += (p0 + p1) + (p2 + p3);
                pk[t16][ni][0] = (uint32_t)f2bf(p0) | ((uint32_t)f2bf(p1) << 16);
                pk[t16][ni][1] = (uint32_t)f2bf(p2) | ((uint32_t)f2bf(p3) << 16);
            }
            rs += __shfl_xor(rs, 16);
            rs += __shfl_xor(rs, 32);
            lrow[t16] = lrow[t16] * alpha + rs;
#pragma unroll
            for (int tile = 0; tile < 8; tile++)
#pragma unroll
                for (int r = 0; r < 4; r++) yacc[t16][tile][r] *= alpha;
        }

        // Y^T += V^T * P^T : A = Vs (tau-permuted cols), B = pk registers directly
#pragma unroll
        for (int ks2 = 0; ks2 < 2; ks2++) {
            union { uint32_t u[4]; bf16x8 v; } pf0, pf1;
            pf0.u[0] = pk[0][2 * ks2][0];     pf0.u[1] = pk[0][2 * ks2][1];
            pf0.u[2] = pk[0][2 * ks2 + 1][0]; pf0.u[3] = pk[0][2 * ks2 + 1][1];
            pf1.u[0] = pk[1][2 * ks2][0];     pf1.u[1] = pk[1][2 * ks2][1];
            pf1.u[2] = pk[1][2 * ks2 + 1][0]; pf1.u[3] = pk[1][2 * ks2 + 1][1];
#pragma unroll
            for (int tile = 0; tile < 8; tile++) {
                bf16x8 vf = *(const bf16x8*)&Vs[(tile * 16 + l16) * 64 +
                                                ((ks2 * 4 + quad) ^ (l16 & 7)) * 8];
                yacc[0][tile] = __builtin_amdgcn_mfma_f32_16x16x32_bf16(vf, pf0.v, yacc[0][tile], 0, 0, 0);
                yacc[1][tile] = __builtin_amdgcn_mfma_f32_16x16x32_bf16(vf, pf1.v, yacc[1][tile], 0, 0, 0);
            }
        }
    }

    // epilogue: Y^T[d][q] registers -> LDS [q][d] (swizzled) -> coalesced global
    __syncthreads();
#pragma unroll
    for (int t16 = 0; t16 < 2; t16++) {
        float inv = 1.f / lrow[t16];
        int qrow = wave * 32 + t16 * 16 + l16;
#pragma unroll
        for (int tile = 0; tile < 8; tile++) {
#pragma unroll
            for (int cp = 0; cp < 2; cp++) {
                int d = tile * 16 + quad * 4 + cp * 2;
                uint32_t pv = (uint32_t)f2bf(yacc[t16][tile][cp * 2] * inv) |
                              ((uint32_t)f2bf(yacc[t16][tile][cp * 2 + 1] * inv) << 16);
                *(uint32_t*)&smem[qrow * 128 + ((d >> 3) ^ l16) * 8 + (d & 7)] = pv;
            }
        }
    }
    __syncthreads();
#pragma unroll
    for (int i = 0; i < 8; i++) {
        int cc = tid + i * 256;
        int row = cc >> 4, seg = cc & 15;
        uint4 dv = *(const uint4*)&smem[row * 128 + (seg ^ (row & 15)) * 8];
        size_t q = (size_t)(b * T_ + qt * 128 + row);
        *(uint4*)(ya + q * C_ + h * 128 + seg * 8) = dv;
    }
}

extern "C" void kernel_launch(void* const* d_in, const int* in_sizes, int n_in,
                              void* d_out, int out_size, void* d_ws, size_t ws_size,
                              hipStream_t stream) {
    (void)in_sizes; (void)n_in; (void)out_size; (void)ws_size;
    const float* x = (const float*)d_in[0];
    const float* cosb = (const float*)d_in[1];
    const float* sinb = (const float*)d_in[2];
    const float* w_attn = (const float*)d_in[3];
    const float* w_proj = (const float*)d_in[4];
    float* out = (float*)d_out;

    char* ws = (char*)d_ws;
    size_t off = 0;
    auto alloc = [&](size_t bytes) -> char* {
        char* p = ws + off;
        off += (bytes + 255) & ~(size_t)255;
        return p;
    };
    u16* xb  = (u16*)alloc((size_t)4096 * 2048 * 2);
    u16* wat = (u16*)alloc((size_t)3072 * 2048 * 2);
    u16* wpt = (u16*)alloc((size_t)2048 * 2048 * 2);
    u16* qkv = (u16*)alloc((size_t)4096 * 3072 * 2);
    u16* qa  = (u16*)alloc((size_t)B_ * NH * T_ * HS * 2);
    u16* ka  = (u16*)alloc((size_t)B_ * NG * T_ * HS * 2);
    u16* vt  = (u16*)alloc((size_t)B_ * NG * T_ * HS * 2);
    u16* ya  = xb; // xb dead after gemm1

    k_f32_to_bf16<<<dim3(8192), dim3(256), 0, stream>>>(x, xb, 4096 * 2048 / 4);
    k_transpose_bf16<<<dim3(96, 64), dim3(256), 0, stream>>>(w_attn, wat, 2048, 3072);
    k_transpose_bf16<<<dim3(64, 64), dim3(256), 0, stream>>>(w_proj, wpt, 2048, 2048);
    k_gemm_bt<u16><<<dim3(24, 32), dim3(256), 0, stream>>>(xb, wat, qkv, 4096, 3072, 2048);
    k_rope_pack<<<dim3(4096), dim3(256), 0, stream>>>(qkv, cosb, sinb, qa, ka, vt);
    k_attn<<<dim3(16, 16, 2), dim3(256), 0, stream>>>(qa, ka, vt, ya);
    k_gemm_bt<float><<<dim3(16, 32), dim3(256), 0, stream>>>(ya, wpt, out, 4096, 2048, 2048);
}